// Round 1
// 162.044 us; speedup vs baseline: 1.0732x; 1.0732x over previous
//
#include <hip/hip_runtime.h>

#define NN 2048
#define HALF 1024
#define CC 128
#define EE 65536
#define CAP 128

typedef unsigned short u16;

__device__ __forceinline__ float sigm(float v){ return 1.0f/(1.0f + __expf(-v)); }

__device__ __forceinline__ float dinv_lo(int i, const int* __restrict__ cnt,
                                         const float* __restrict__ colsum){
  return rsqrtf(1.0f + (float)cnt[i] + colsum[i]);
}
__device__ __forceinline__ float dinv_any(int i, const int* __restrict__ cnt,
                                          const float* __restrict__ colsum){
  float cs = (i < HALF) ? colsum[i] : 0.0f;
  return rsqrtf(1.0f + (float)cnt[i] + cs);
}

// ---------------- K1: prep (640 blocks)
//  all blocks: strided zero of AGG1 + bias-seed of out (plain float4 stores)
//  [0,128):   SpRaw[r][c]=sigm(my[r][c]) (coalesced) + colsum atomics
//  [128,384): bucket sparse edges by dst
//  [384,640): H0 = x @ W1  (8 rows/block, LDS-staged, b128 LDS reads)
__global__ __launch_bounds__(256) void k_prep(
    const float* __restrict__ my, const int* __restrict__ ei, const float* __restrict__ x,
    const float* __restrict__ W1,
    const float* __restrict__ bmu, const float* __restrict__ bls,
    float* __restrict__ SpRaw, float* __restrict__ colsum,
    int* __restrict__ cnt, u16* __restrict__ bucket, float* __restrict__ H0,
    float* __restrict__ AGG1, float* __restrict__ out)
{
  __shared__ float la[8][CC];
  int b = blockIdx.x, t = threadIdx.x;
  int gid = b*256 + t;                    // 0..163839
  if (gid < 65536) {
    ((float4*)AGG1)[gid] = make_float4(0.f,0.f,0.f,0.f);
  } else if (gid < 131072) {
    int i = gid - 65536;                  // float4 index into out (65536 total)
    int g4 = (i & 15)*4;
    const float* bb = (i < 32768) ? bmu : bls;
    ((float4*)out)[i] = make_float4(bb[g4], bb[g4+1], bb[g4+2], bb[g4+3]);
  }

  if (b < 128) {
    int c0 = t*4;
    float cs0=0.f, cs1=0.f, cs2=0.f, cs3=0.f;
    #pragma unroll 2
    for (int rr=0; rr<8; ++rr){
      int r = b*8 + rr;
      float4 v = *(const float4*)(my + (size_t)r*NN + c0);
      float s0=sigm(v.x), s1=sigm(v.y), s2=sigm(v.z), s3=sigm(v.w);
      *(float4*)(SpRaw + (size_t)r*HALF + c0) = make_float4(s0,s1,s2,s3);
      cs0+=s0; cs1+=s1; cs2+=s2; cs3+=s3;
    }
    atomicAdd(&colsum[c0+0], cs0);
    atomicAdd(&colsum[c0+1], cs1);
    atomicAdd(&colsum[c0+2], cs2);
    atomicAdd(&colsum[c0+3], cs3);
  } else if (b < 384) {
    int e = (b-128)*256 + t;
    int s = ei[e], d = ei[EE + e];
    int slot = atomicAdd(&cnt[d], 1);
    if (slot < CAP) bucket[d*CAP + slot] = (u16)s;
  } else {
    int row0 = (b-384)*8;
    #pragma unroll
    for (int i=0;i<4;i++){
      int idx = i*256 + t;
      la[idx>>7][idx&127] = x[(size_t)row0*CC + idx];
    }
    __syncthreads();
    int f = t & 127, rh = t >> 7;
    const float4* a0 = (const float4*)la[rh*4+0];
    const float4* a1 = (const float4*)la[rh*4+1];
    const float4* a2 = (const float4*)la[rh*4+2];
    const float4* a3 = (const float4*)la[rh*4+3];
    float o0=0.f, o1=0.f, o2=0.f, o3=0.f;
    #pragma unroll 4
    for (int k4=0;k4<32;k4++){
      float4 v0=a0[k4], v1=a1[k4], v2=a2[k4], v3=a3[k4];
      float w0 = W1[(k4*4+0)*CC + f];
      float w1 = W1[(k4*4+1)*CC + f];
      float w2 = W1[(k4*4+2)*CC + f];
      float w3 = W1[(k4*4+3)*CC + f];
      o0=fmaf(v0.x,w0,o0); o0=fmaf(v0.y,w1,o0); o0=fmaf(v0.z,w2,o0); o0=fmaf(v0.w,w3,o0);
      o1=fmaf(v1.x,w0,o1); o1=fmaf(v1.y,w1,o1); o1=fmaf(v1.z,w2,o1); o1=fmaf(v1.w,w3,o1);
      o2=fmaf(v2.x,w0,o2); o2=fmaf(v2.y,w1,o2); o2=fmaf(v2.z,w2,o2); o2=fmaf(v2.w,w3,o2);
      o3=fmaf(v3.x,w0,o3); o3=fmaf(v3.y,w1,o3); o3=fmaf(v3.z,w2,o3); o3=fmaf(v3.w,w3,o3);
    }
    H0[(size_t)(row0 + rh*4 + 0)*CC + f] = o0;
    H0[(size_t)(row0 + rh*4 + 1)*CC + f] = o1;
    H0[(size_t)(row0 + rh*4 + 2)*CC + f] = o2;
    H0[(size_t)(row0 + rh*4 + 3)*CC + f] = o3;
  }
}

// ---------------- K2: AGG1 = Â H0
//  LDS dinv table built once per block (kills per-edge cnt/colsum/rsqrt).
//  dense [0,256): 16 cols/block, 4 r-chunks, float2-per-lane
//  sparse [256,768): 1 wave per dst (float2), bucket consumed in u32 pairs
__global__ __launch_bounds__(256) void k_layer1(
  const float* __restrict__ SpRaw, const float* __restrict__ F,
  const int* __restrict__ cnt, const float* __restrict__ colsum,
  const u16* __restrict__ bucket, float* __restrict__ AGG)
{
  __shared__ float sdinv[NN];
  int b = blockIdx.x, t = threadIdx.x;
  #pragma unroll
  for (int i=0;i<8;i++){
    int j = i*256 + t;
    float cs = (j < HALF) ? colsum[j] : 0.0f;
    sdinv[j] = rsqrtf(1.0f + (float)cnt[j] + cs);
  }
  __syncthreads();
  int lane = t & 63, f0 = lane*2;
  if (b < 256) {
    int dbase = (b>>2)*16 + (t>>6)*4;
    int r0 = (b&3)*256;
    float a00=0.f,a01=0.f,a10=0.f,a11=0.f,a20=0.f,a21=0.f,a30=0.f,a31=0.f;
    #pragma unroll 4
    for (int rr=0; rr<256; ++rr){
      int r = r0 + rr;
      float2 fv = *(const float2*)(F + (size_t)r*CC + f0);
      float sc = sdinv[r];
      float fx = fv.x*sc, fy = fv.y*sc;
      float4 s4 = *(const float4*)(SpRaw + (size_t)r*HALF + dbase);
      a00=fmaf(s4.x,fx,a00); a01=fmaf(s4.x,fy,a01);
      a10=fmaf(s4.y,fx,a10); a11=fmaf(s4.y,fy,a11);
      a20=fmaf(s4.z,fx,a20); a21=fmaf(s4.z,fy,a21);
      a30=fmaf(s4.w,fx,a30); a31=fmaf(s4.w,fy,a31);
    }
    float d0=sdinv[dbase+0], d1=sdinv[dbase+1], d2=sdinv[dbase+2], d3=sdinv[dbase+3];
    float* o = AGG + (size_t)dbase*CC + f0;
    atomicAdd(o + 0*CC + 0, a00*d0); atomicAdd(o + 0*CC + 1, a01*d0);
    atomicAdd(o + 1*CC + 0, a10*d1); atomicAdd(o + 1*CC + 1, a11*d1);
    atomicAdd(o + 2*CC + 0, a20*d2); atomicAdd(o + 2*CC + 1, a21*d2);
    atomicAdd(o + 3*CC + 0, a30*d3); atomicAdd(o + 3*CC + 1, a31*d3);
  } else {
    int d = (b-256)*4 + (t>>6);
    float dd = sdinv[d];
    float2 sv = *(const float2*)(F + (size_t)d*CC + f0);
    float ax = dd*sv.x, ay = dd*sv.y;          // self-loop term
    int m = cnt[d]; m = m > CAP ? CAP : m;
    const u16* bk = bucket + d*CAP;
    int j = 0;
    for (; j+1 < m; j += 2){
      unsigned pr = *(const unsigned*)(bk + j);
      int s0 = pr & 0xffff, s1 = pr >> 16;
      float w0 = sdinv[s0], w1 = sdinv[s1];
      float2 v0 = *(const float2*)(F + (size_t)s0*CC + f0);
      float2 v1 = *(const float2*)(F + (size_t)s1*CC + f0);
      ax = fmaf(w0, v0.x, ax); ay = fmaf(w0, v0.y, ay);
      ax = fmaf(w1, v1.x, ax); ay = fmaf(w1, v1.y, ay);
    }
    if (j < m){
      int s0 = bk[j];
      float w0 = sdinv[s0];
      float2 v0 = *(const float2*)(F + (size_t)s0*CC + f0);
      ax = fmaf(w0, v0.x, ax); ay = fmaf(w0, v0.y, ay);
    }
    atomicAdd(&AGG[(size_t)d*CC + f0    ], dd*ax);
    atomicAdd(&AGG[(size_t)d*CC + f0 + 1], dd*ay);
  }
}

// ---------------- K3: mid (256 blocks): G' = ( relu(AGG1 + b1) @ [Wmu|Wls] ) * dinv[row]
__global__ __launch_bounds__(256) void k_mid(
  const float* __restrict__ AGG1, const float* __restrict__ b1,
  const float* __restrict__ Wmu, const float* __restrict__ Wls,
  const int* __restrict__ cnt, const float* __restrict__ colsum,
  float* __restrict__ G)
{
  __shared__ float la[8][CC];
  int b = blockIdx.x, t = threadIdx.x;
  int row0 = b*8;
  #pragma unroll
  for (int i=0;i<4;i++){
    int idx = i*256 + t;
    float v = AGG1[(size_t)row0*CC + idx] + b1[idx & 127];
    la[idx>>7][idx&127] = v > 0.f ? v : 0.f;
  }
  __syncthreads();
  int f = t & 127, rh = t >> 7;
  int g = f & 63;
  const float* W = (f < 64) ? Wmu : Wls;
  const float4* a0 = (const float4*)la[rh*4+0];
  const float4* a1 = (const float4*)la[rh*4+1];
  const float4* a2 = (const float4*)la[rh*4+2];
  const float4* a3 = (const float4*)la[rh*4+3];
  float o0=0.f, o1=0.f, o2=0.f, o3=0.f;
  #pragma unroll 4
  for (int k4=0;k4<32;k4++){
    float4 v0=a0[k4], v1=a1[k4], v2=a2[k4], v3=a3[k4];
    float w0 = W[(k4*4+0)*64 + g];
    float w1 = W[(k4*4+1)*64 + g];
    float w2 = W[(k4*4+2)*64 + g];
    float w3 = W[(k4*4+3)*64 + g];
    o0=fmaf(v0.x,w0,o0); o0=fmaf(v0.y,w1,o0); o0=fmaf(v0.z,w2,o0); o0=fmaf(v0.w,w3,o0);
    o1=fmaf(v1.x,w0,o1); o1=fmaf(v1.y,w1,o1); o1=fmaf(v1.z,w2,o1); o1=fmaf(v1.w,w3,o1);
    o2=fmaf(v2.x,w0,o2); o2=fmaf(v2.y,w1,o2); o2=fmaf(v2.z,w2,o2); o2=fmaf(v2.w,w3,o2);
    o3=fmaf(v3.x,w0,o3); o3=fmaf(v3.y,w1,o3); o3=fmaf(v3.z,w2,o3); o3=fmaf(v3.w,w3,o3);
  }
  {
    int row = row0 + rh*4 + 0; G[(size_t)row*CC + f] = o0 * dinv_any(row, cnt, colsum);
  }
  { int row = row0 + rh*4 + 1; G[(size_t)row*CC + f] = o1 * dinv_any(row, cnt, colsum); }
  { int row = row0 + rh*4 + 2; G[(size_t)row*CC + f] = o2 * dinv_any(row, cnt, colsum); }
  { int row = row0 + rh*4 + 3; G[(size_t)row*CC + f] = o3 * dinv_any(row, cnt, colsum); }
}

// ---------------- K4: out += Â-apply on pre-scaled G'  (atomics into bias-seeded d_out)
//  dense [0,256): float2-per-lane; sparse [256,768): 1 wave per dst, paired bucket
__global__ __launch_bounds__(256) void k_layer2(
  const float* __restrict__ SpRaw, const float* __restrict__ G,
  const int* __restrict__ cnt, const float* __restrict__ colsum,
  const u16* __restrict__ bucket, float* __restrict__ out)
{
  int b = blockIdx.x, t = threadIdx.x;
  int lane = t & 63, f0 = lane*2;
  size_t obase = (f0 < 64) ? 0 : (size_t)NN*64;
  int g0 = f0 & 63;
  if (b < 256) {
    int dbase = (b>>2)*16 + (t>>6)*4;
    int r0 = (b&3)*256;
    float a00=0.f,a01=0.f,a10=0.f,a11=0.f,a20=0.f,a21=0.f,a30=0.f,a31=0.f;
    #pragma unroll 4
    for (int rr=0; rr<256; ++rr){
      int r = r0 + rr;
      float2 gv = *(const float2*)(G + (size_t)r*CC + f0);   // already dinv[r]-scaled
      float4 s4 = *(const float4*)(SpRaw + (size_t)r*HALF + dbase);
      a00=fmaf(s4.x,gv.x,a00); a01=fmaf(s4.x,gv.y,a01);
      a10=fmaf(s4.y,gv.x,a10); a11=fmaf(s4.y,gv.y,a11);
      a20=fmaf(s4.z,gv.x,a20); a21=fmaf(s4.z,gv.y,a21);
      a30=fmaf(s4.w,gv.x,a30); a31=fmaf(s4.w,gv.y,a31);
    }
    float d0=dinv_lo(dbase+0,cnt,colsum), d1=dinv_lo(dbase+1,cnt,colsum);
    float d2=dinv_lo(dbase+2,cnt,colsum), d3=dinv_lo(dbase+3,cnt,colsum);
    float* o = out + obase + (size_t)dbase*64 + g0;
    atomicAdd(o + 0*64 + 0, a00*d0); atomicAdd(o + 0*64 + 1, a01*d0);
    atomicAdd(o + 1*64 + 0, a10*d1); atomicAdd(o + 1*64 + 1, a11*d1);
    atomicAdd(o + 2*64 + 0, a20*d2); atomicAdd(o + 2*64 + 1, a21*d2);
    atomicAdd(o + 3*64 + 0, a30*d3); atomicAdd(o + 3*64 + 1, a31*d3);
  } else {
    int d = (b-256)*4 + (t>>6);
    float2 a = *(const float2*)(G + (size_t)d*CC + f0);      // self term (pre-scaled)
    float ax = a.x, ay = a.y;
    int m = cnt[d]; m = m > CAP ? CAP : m;
    const u16* bk = bucket + d*CAP;
    int j = 0;
    for (; j+1 < m; j += 2){
      unsigned pr = *(const unsigned*)(bk + j);
      int s0 = pr & 0xffff, s1 = pr >> 16;
      float2 v0 = *(const float2*)(G + (size_t)s0*CC + f0);
      float2 v1 = *(const float2*)(G + (size_t)s1*CC + f0);
      ax += v0.x + v1.x; ay += v0.y + v1.y;
    }
    if (j < m){
      int s0 = bk[j];
      float2 v0 = *(const float2*)(G + (size_t)s0*CC + f0);
      ax += v0.x; ay += v0.y;
    }
    float dd = dinv_any(d, cnt, colsum);
    atomicAdd(&out[obase + (size_t)d*64 + g0    ], dd*ax);
    atomicAdd(&out[obase + (size_t)d*64 + g0 + 1], dd*ay);
  }
}

extern "C" void kernel_launch(void* const* d_in, const int* in_sizes, int n_in,
                              void* d_out, int out_size, void* d_ws, size_t ws_size,
                              hipStream_t stream)
{
  (void)in_sizes; (void)n_in; (void)out_size; (void)ws_size;
  const float* x   = (const float*)d_in[0];
  const float* my  = (const float*)d_in[1];
  const float* W1  = (const float*)d_in[2];
  const float* b1  = (const float*)d_in[3];
  const float* Wmu = (const float*)d_in[4];
  const float* bmu = (const float*)d_in[5];
  const float* Wls = (const float*)d_in[6];
  const float* bls = (const float*)d_in[7];
  const int*   ei  = (const int*)d_in[8];
  float* out = (float*)d_out;
  char* ws = (char*)d_ws;

  // ws layout — memset covers only [0, 12288): cnt, colsum
  int*   cnt    = (int*)  (ws + 0);        //    8192 B (memset 0)
  float* colsum = (float*)(ws + 8192);     //    4096 B (memset 0)
  float* AGG1   = (float*)(ws + 12288);    // 1048576 B (zeroed in k_prep)
  u16*   bucket = (u16*)  (ws + 1060864);  //  524288 B
  float* SpRaw  = (float*)(ws + 1585152);  // 4194304 B
  float* H0     = (float*)(ws + 5779456);  // 1048576 B
  float* G      = (float*)(ws + 6828032);  // 1048576 B

  hipMemsetAsync(ws, 0, 12288, stream);
  k_prep  <<<640, 256, 0, stream>>>(my, ei, x, W1, bmu, bls,
                                    SpRaw, colsum, cnt, bucket, H0, AGG1, out);
  k_layer1<<<768, 256, 0, stream>>>(SpRaw, H0, cnt, colsum, bucket, AGG1);
  k_mid   <<<256, 256, 0, stream>>>(AGG1, b1, Wmu, Wls, cnt, colsum, G);
  k_layer2<<<768, 256, 0, stream>>>(SpRaw, G, cnt, colsum, bucket, out);
}